// Round 1
// baseline (3107.374 us; speedup 1.0000x reference)
//
#include <hip/hip_runtime.h>
#include <hip/hip_fp16.h>

// N=1024, F=22, T=1000, H=64, gates 4H=256
#define TT 1000
#define FF 22
#define HH 64
#define BB 16      // batch per block
#define NBLK 64    // 1024/16
#define S0 112     // LDS row stride (f16) layer0 input [x(0:22)|pad|h0(32:96)|pad], K tiles=3
#define S1 144     // LDS row stride (f16) layers1/2 [h_in(0:64)|h_rec(64:128)|pad], K tiles=4

typedef _Float16 half8 __attribute__((ext_vector_type(8)));
typedef float float4v __attribute__((ext_vector_type(4)));

__device__ __forceinline__ float sigm(float v) { return 1.0f / (1.0f + __expf(-v)); }
__device__ __forceinline__ float tanh_(float v) { return 1.0f - 2.0f / (__expf(2.0f * v) + 1.0f); }

extern "C" __global__ void __launch_bounds__(256, 1)
lstm_fused(const float* __restrict__ x,
           const float* __restrict__ Wih0, const float* __restrict__ Whh0,
           const float* __restrict__ bih0, const float* __restrict__ bhh0,
           const float* __restrict__ Wih1, const float* __restrict__ Whh1,
           const float* __restrict__ bih1, const float* __restrict__ bhh1,
           const float* __restrict__ Wih2, const float* __restrict__ Whh2,
           const float* __restrict__ bih2, const float* __restrict__ bhh2,
           const float* __restrict__ w0, const float* __restrict__ b0,
           const float* __restrict__ w1, const float* __restrict__ b1,
           const float* __restrict__ w2, const float* __restrict__ b2,
           const float* __restrict__ w3, const float* __restrict__ b3,
           const float* __restrict__ g0, const float* __restrict__ be0,
           const float* __restrict__ m0, const float* __restrict__ v0,
           const float* __restrict__ g1, const float* __restrict__ be1,
           const float* __restrict__ m1, const float* __restrict__ v1,
           const float* __restrict__ g2, const float* __restrict__ be2,
           const float* __restrict__ m2, const float* __restrict__ v2,
           float* __restrict__ out)
{
    __shared__ __align__(16) _Float16 in0[2 * BB * S0];
    __shared__ __align__(16) _Float16 in1[2 * BB * S1];
    __shared__ __align__(16) _Float16 in2[2 * BB * S1];
    __shared__ float fcA[BB * 64];
    __shared__ float fcB[BB * 64];
    __shared__ float fcW[54 * 65];   // padded stride per-layer to kill bank conflicts
    __shared__ float fcP[5 * 64];    // bias, gamma, beta, mean, var staging

    const int tid = threadIdx.x;
    const int w   = tid >> 6;     // wave 0..3
    const int l   = tid & 63;     // lane
    const int q   = l >> 4;       // quad 0..3
    const int l15 = l & 15;
    const int col = 16 * w + l15; // hidden-unit column u in [0,64)
    const int n0  = blockIdx.x * BB;

    // ---- zero LDS tick buffers (pads must be 0, h states start 0) ----
    for (int i = tid; i < 2 * BB * S0; i += 256) in0[i] = (_Float16)0.0f;
    for (int i = tid; i < 2 * BB * S1; i += 256) in1[i] = (_Float16)0.0f;
    for (int i = tid; i < 2 * BB * S1; i += 256) in2[i] = (_Float16)0.0f;

    // ---- build weight B-fragments in registers ----
    // B-frag (16x16x32): lane holds B[k = 8*quad + j][n = lane&15] for k-tile kt.
    // Our GEMM: Z[b][row] = sum_k A[b][k] * W[row][mapk(k)], row = 64*g + col.
    half8 wf0[4][3], wf1[4][4], wf2[4][4];
    float biasv[3][4];
#pragma unroll
    for (int g = 0; g < 4; ++g) {
        const int row = 64 * g + col;
#pragma unroll
        for (int kt = 0; kt < 3; ++kt) {
            half8 h{};
#pragma unroll
            for (int j = 0; j < 8; ++j) {
                const int k = 32 * kt + 8 * q + j;
                float val = 0.0f;
                if (k < 32) { if (k < FF) val = Wih0[row * FF + k]; }
                else        { val = Whh0[row * HH + (k - 32)]; }
                h[j] = (_Float16)val;
            }
            wf0[g][kt] = h;
        }
        biasv[0][g] = bih0[row] + bhh0[row];
#pragma unroll
        for (int kt = 0; kt < 4; ++kt) {
            half8 ha{}, hb{};
#pragma unroll
            for (int j = 0; j < 8; ++j) {
                const int k = 32 * kt + 8 * q + j;
                ha[j] = (_Float16)((k < 64) ? Wih1[row * HH + k] : Whh1[row * HH + (k - 64)]);
                hb[j] = (_Float16)((k < 64) ? Wih2[row * HH + k] : Whh2[row * HH + (k - 64)]);
            }
            wf1[g][kt] = ha;
            wf2[g][kt] = hb;
        }
        biasv[1][g] = bih1[row] + bhh1[row];
        biasv[2][g] = bih2[row] + bhh2[row];
    }

    // ---- x staging assignment: item i -> (b = i/22, f = i%22), strided loads ----
    const int i0i = tid, i1i = tid + 256;
    const int xb0 = i0i / FF, xf0 = i0i - xb0 * FF;
    const int xb1 = i1i / FF, xf1 = i1i - xb1 * FF;
    const bool x1ok = (i1i < BB * FF); // 352 items
    const float* xp0p = x + ((size_t)(n0 + xb0) * FF + xf0) * TT;
    const float* xp1p = x + ((size_t)(n0 + (x1ok ? xb1 : 0)) * FF + (x1ok ? xf1 : 0)) * TT;

    __syncthreads(); // zero-init visible

    // stage x_0 into in0[parity 0]
    {
        float a = xp0p[0];
        in0[xb0 * S0 + xf0] = (_Float16)a;
        if (x1ok) { float bv = xp1p[0]; in0[xb1 * S0 + xf1] = (_Float16)bv; }
    }
    __syncthreads();

    const int arow0 = l15 * S0 + q * 8; // A-frag read base (f16 units)
    const int arow1 = l15 * S1 + q * 8;

    float c0[4] = {0.f, 0.f, 0.f, 0.f};
    float c1[4] = {0.f, 0.f, 0.f, 0.f};
    float c2[4] = {0.f, 0.f, 0.f, 0.f};

    for (int t = 0; t < TT; ++t) {
        const int p = t & 1;
        _Float16* i0r = in0 + p * BB * S0;
        _Float16* i0w = in0 + (p ^ 1) * BB * S0;
        _Float16* i1r = in1 + p * BB * S1;
        _Float16* i1w = in1 + (p ^ 1) * BB * S1;
        _Float16* i2r = in2 + p * BB * S1;
        _Float16* i2w = in2 + (p ^ 1) * BB * S1;

        // prefetch x_{t+1}
        float xr0 = 0.f, xr1 = 0.f;
        const bool hasNext = (t + 1 < TT);
        if (hasNext) {
            xr0 = xp0p[t + 1];
            if (x1ok) xr1 = xp1p[t + 1];
        }

        // ================= layer 0 =================
        {
            float4v acc[4];
#pragma unroll
            for (int g = 0; g < 4; ++g)
                acc[g] = float4v{biasv[0][g], biasv[0][g], biasv[0][g], biasv[0][g]};
#pragma unroll
            for (int kt = 0; kt < 3; ++kt) {
                half8 a = *(const half8*)(i0r + arow0 + 32 * kt);
#pragma unroll
                for (int g = 0; g < 4; ++g)
                    acc[g] = __builtin_amdgcn_mfma_f32_16x16x32_f16(a, wf0[g][kt], acc[g], 0, 0, 0);
            }
#pragma unroll
            for (int r = 0; r < 4; ++r) {
                const int b = 4 * q + r;
                float cc = sigm(acc[1][r]) * c0[r] + sigm(acc[0][r]) * tanh_(acc[2][r]);
                c0[r] = cc;
                float hh = sigm(acc[3][r]) * tanh_(cc);
                _Float16 hf = (_Float16)hh;
                i0w[b * S0 + 32 + col] = hf; // own recurrence, next tick
                i1r[b * S1 + col]      = hf; // layer1 input, this tick
            }
        }
        __syncthreads();

        // ================= layer 1 =================
        {
            float4v acc[4];
#pragma unroll
            for (int g = 0; g < 4; ++g)
                acc[g] = float4v{biasv[1][g], biasv[1][g], biasv[1][g], biasv[1][g]};
#pragma unroll
            for (int kt = 0; kt < 4; ++kt) {
                half8 a = *(const half8*)(i1r + arow1 + 32 * kt);
#pragma unroll
                for (int g = 0; g < 4; ++g)
                    acc[g] = __builtin_amdgcn_mfma_f32_16x16x32_f16(a, wf1[g][kt], acc[g], 0, 0, 0);
            }
#pragma unroll
            for (int r = 0; r < 4; ++r) {
                const int b = 4 * q + r;
                float cc = sigm(acc[1][r]) * c1[r] + sigm(acc[0][r]) * tanh_(acc[2][r]);
                c1[r] = cc;
                float hh = sigm(acc[3][r]) * tanh_(cc);
                _Float16 hf = (_Float16)hh;
                i1w[b * S1 + 64 + col] = hf; // own recurrence
                i2r[b * S1 + col]      = hf; // layer2 input, this tick
            }
        }
        __syncthreads();

        // ================= layer 2 =================
        {
            float4v acc[4];
#pragma unroll
            for (int g = 0; g < 4; ++g)
                acc[g] = float4v{biasv[2][g], biasv[2][g], biasv[2][g], biasv[2][g]};
#pragma unroll
            for (int kt = 0; kt < 4; ++kt) {
                half8 a = *(const half8*)(i2r + arow1 + 32 * kt);
#pragma unroll
                for (int g = 0; g < 4; ++g)
                    acc[g] = __builtin_amdgcn_mfma_f32_16x16x32_f16(a, wf2[g][kt], acc[g], 0, 0, 0);
            }
#pragma unroll
            for (int r = 0; r < 4; ++r) {
                const int b = 4 * q + r;
                float cc = sigm(acc[1][r]) * c2[r] + sigm(acc[0][r]) * tanh_(acc[2][r]);
                c2[r] = cc;
                float hh = sigm(acc[3][r]) * tanh_(cc);
                i2w[b * S1 + 64 + col] = (_Float16)hh;
                if (t == TT - 1) fcA[b * 64 + col] = hh; // final h2 in fp32
            }
        }

        // stage x_{t+1}
        if (hasNext) {
            i0w[xb0 * S0 + xf0] = (_Float16)xr0;
            if (x1ok) i0w[xb1 * S0 + xf1] = (_Float16)xr1;
        }
        __syncthreads();
    }

    // ================= FC head (fp32) =================
    // FC0: 64 -> 54, BN, ReLU   (fcA -> fcB)
    for (int i = tid; i < 54 * 64; i += 256) fcW[(i >> 6) * 65 + (i & 63)] = w0[i];
    for (int i = tid; i < 54; i += 256) {
        fcP[i] = b0[i]; fcP[64 + i] = g0[i]; fcP[128 + i] = be0[i];
        fcP[192 + i] = m0[i]; fcP[256 + i] = v0[i];
    }
    __syncthreads();
    for (int idx = tid; idx < BB * 54; idx += 256) {
        const int b = idx / 54, j = idx - b * 54;
        float s = fcP[j];
        for (int k = 0; k < 64; ++k) s += fcW[j * 65 + k] * fcA[b * 64 + k];
        s = (s - fcP[192 + j]) * rsqrtf(fcP[256 + j] + 1e-5f) * fcP[64 + j] + fcP[128 + j];
        fcB[b * 64 + j] = fmaxf(s, 0.0f);
    }
    __syncthreads();

    // FC1: 54 -> 44, BN, ReLU   (fcB -> fcA)
    for (int i = tid; i < 44 * 54; i += 256) fcW[(i / 54) * 55 + (i % 54)] = w1[i];
    for (int i = tid; i < 44; i += 256) {
        fcP[i] = b1[i]; fcP[64 + i] = g1[i]; fcP[128 + i] = be1[i];
        fcP[192 + i] = m1[i]; fcP[256 + i] = v1[i];
    }
    __syncthreads();
    for (int idx = tid; idx < BB * 44; idx += 256) {
        const int b = idx / 44, j = idx - b * 44;
        float s = fcP[j];
        for (int k = 0; k < 54; ++k) s += fcW[j * 55 + k] * fcB[b * 64 + k];
        s = (s - fcP[192 + j]) * rsqrtf(fcP[256 + j] + 1e-5f) * fcP[64 + j] + fcP[128 + j];
        fcA[b * 64 + j] = fmaxf(s, 0.0f);
    }
    __syncthreads();

    // FC2: 44 -> 24, BN, ReLU   (fcA -> fcB)
    for (int i = tid; i < 24 * 44; i += 256) fcW[(i / 44) * 45 + (i % 44)] = w2[i];
    for (int i = tid; i < 24; i += 256) {
        fcP[i] = b2[i]; fcP[64 + i] = g2[i]; fcP[128 + i] = be2[i];
        fcP[192 + i] = m2[i]; fcP[256 + i] = v2[i];
    }
    __syncthreads();
    for (int idx = tid; idx < BB * 24; idx += 256) {
        const int b = idx / 24, j = idx - b * 24;
        float s = fcP[j];
        for (int k = 0; k < 44; ++k) s += fcW[j * 45 + k] * fcA[b * 64 + k];
        s = (s - fcP[192 + j]) * rsqrtf(fcP[256 + j] + 1e-5f) * fcP[64 + j] + fcP[128 + j];
        fcB[b * 64 + j] = fmaxf(s, 0.0f);
    }
    __syncthreads();

    // FC3: 24 -> 4 -> global out
    for (int i = tid; i < 4 * 24; i += 256) fcW[(i / 24) * 25 + (i % 24)] = w3[i];
    for (int i = tid; i < 4; i += 256) fcP[i] = b3[i];
    __syncthreads();
    for (int idx = tid; idx < BB * 4; idx += 256) {
        const int b = idx / 4, j = idx - b * 4;
        float s = fcP[j];
        for (int k = 0; k < 24; ++k) s += fcW[j * 25 + k] * fcB[b * 64 + k];
        out[(size_t)(n0 + b) * 4 + j] = s;
    }
}

extern "C" void kernel_launch(void* const* d_in, const int* in_sizes, int n_in,
                              void* d_out, int out_size, void* d_ws, size_t ws_size,
                              hipStream_t stream) {
    const float* p[33];
    for (int i = 0; i < 33; ++i) p[i] = (const float*)d_in[i];
    lstm_fused<<<NBLK, 256, 0, stream>>>(
        p[0],
        p[1], p[2], p[3], p[4],
        p[5], p[6], p[7], p[8],
        p[9], p[10], p[11], p[12],
        p[13], p[14], p[15], p[16], p[17], p[18], p[19], p[20],
        p[21], p[22], p[23], p[24],
        p[25], p[26], p[27], p[28],
        p[29], p[30], p[31], p[32],
        (float*)d_out);
}

// Round 2
// 1986.942 us; speedup vs baseline: 1.5639x; 1.5639x over previous
//
#include <hip/hip_runtime.h>
#include <hip/hip_fp16.h>

// N=1024, F=22, T=1000, H=64, gates 4H=256
#define TT 1000
#define FF 22
#define HH 64
#define BB 4       // batch per block (M-tile padded to 16; valid C rows land in quad 0)
#define NBLK 256   // 1024/4 -> one block per CU
#define S0 112     // LDS row stride (f16) layer0 input [x(0:22)|pad|h0(32:96)|pad], K tiles=3
#define S1 144     // LDS row stride (f16) layers1/2 [h_in(0:64)|h_rec(64:128)|pad], K tiles=4

typedef _Float16 half8 __attribute__((ext_vector_type(8)));
typedef float float4v __attribute__((ext_vector_type(4)));

__device__ __forceinline__ float sigm(float v) { return 1.0f / (1.0f + __expf(-v)); }
__device__ __forceinline__ float tanh_(float v) { return 1.0f - 2.0f / (__expf(2.0f * v) + 1.0f); }

extern "C" __global__ void __launch_bounds__(256, 1)
lstm_fused(const float* __restrict__ x,
           const float* __restrict__ Wih0, const float* __restrict__ Whh0,
           const float* __restrict__ bih0, const float* __restrict__ bhh0,
           const float* __restrict__ Wih1, const float* __restrict__ Whh1,
           const float* __restrict__ bih1, const float* __restrict__ bhh1,
           const float* __restrict__ Wih2, const float* __restrict__ Whh2,
           const float* __restrict__ bih2, const float* __restrict__ bhh2,
           const float* __restrict__ w0, const float* __restrict__ b0,
           const float* __restrict__ w1, const float* __restrict__ b1,
           const float* __restrict__ w2, const float* __restrict__ b2,
           const float* __restrict__ w3, const float* __restrict__ b3,
           const float* __restrict__ g0, const float* __restrict__ be0,
           const float* __restrict__ m0, const float* __restrict__ v0,
           const float* __restrict__ g1, const float* __restrict__ be1,
           const float* __restrict__ m1, const float* __restrict__ v1,
           const float* __restrict__ g2, const float* __restrict__ be2,
           const float* __restrict__ m2, const float* __restrict__ v2,
           float* __restrict__ out)
{
    __shared__ __align__(16) _Float16 in0[2 * 16 * S0];
    __shared__ __align__(16) _Float16 in1[2 * 16 * S1];
    __shared__ __align__(16) _Float16 in2[2 * 16 * S1];
    __shared__ float fcA[BB * 64];
    __shared__ float fcB[BB * 64];
    __shared__ float fcW[54 * 65];
    __shared__ float fcP[5 * 64];

    const int tid = threadIdx.x;
    const int w   = tid >> 6;     // wave 0..3  (owns gate columns 16w..16w+15)
    const int l   = tid & 63;     // lane
    const int q   = l >> 4;       // quad 0..3
    const int l15 = l & 15;
    const int u   = 16 * w + l15; // this lane's hidden unit (gate-update role)
    const int b   = q;            // this lane's batch row   (gate-update role)
    const int n0  = blockIdx.x * BB;

    // ---- zero LDS tick buffers (pads + unused M rows 4..15 must be 0) ----
    for (int i = tid; i < 2 * 16 * S0; i += 256) in0[i] = (_Float16)0.0f;
    for (int i = tid; i < 2 * 16 * S1; i += 256) in1[i] = (_Float16)0.0f;
    for (int i = tid; i < 2 * 16 * S1; i += 256) in2[i] = (_Float16)0.0f;

    // ---- weight B-fragments in registers ----
    // B-frag (16x16x32): lane holds B[k = 8*q + j][n = l15]; W row = 64*g + u.
    half8 wf0[4][3], wf1[4][4], wf2[4][4];
    float biasv[3][4];
#pragma unroll
    for (int g = 0; g < 4; ++g) {
        const int row = 64 * g + u;
#pragma unroll
        for (int kt = 0; kt < 3; ++kt) {
            half8 h{};
#pragma unroll
            for (int j = 0; j < 8; ++j) {
                const int k = 32 * kt + 8 * q + j;
                float val = 0.0f;
                if (k < 32) { if (k < FF) val = Wih0[row * FF + k]; }
                else        { val = Whh0[row * HH + (k - 32)]; }
                h[j] = (_Float16)val;
            }
            wf0[g][kt] = h;
        }
        biasv[0][g] = bih0[row] + bhh0[row];
#pragma unroll
        for (int kt = 0; kt < 4; ++kt) {
            half8 ha{}, hb{};
#pragma unroll
            for (int j = 0; j < 8; ++j) {
                const int k = 32 * kt + 8 * q + j;
                ha[j] = (_Float16)((k < 64) ? Wih1[row * HH + k] : Whh1[row * HH + (k - 64)]);
                hb[j] = (_Float16)((k < 64) ? Wih2[row * HH + k] : Whh2[row * HH + (k - 64)]);
            }
            wf1[g][kt] = ha;
            wf2[g][kt] = hb;
        }
        biasv[1][g] = bih1[row] + bhh1[row];
        biasv[2][g] = bih2[row] + bhh2[row];
    }

    // ---- x staging: BB*FF = 88 items, one thread each ----
    const bool xok = (tid < BB * FF);
    const int  xb  = xok ? (tid / FF) : 0;
    const int  xf  = xok ? (tid - xb * FF) : 0;
    const float* xp = x + ((size_t)(n0 + xb) * FF + xf) * TT;

    __syncthreads(); // zero-init visible

    if (xok) in0[xb * S0 + xf] = (_Float16)xp[0]; // x_0, parity 0
    __syncthreads();

    const int arow0 = l15 * S0 + q * 8; // A-frag base (f16 units)
    const int arow1 = l15 * S1 + q * 8;

    float c0 = 0.f, c1 = 0.f, c2 = 0.f;

    for (int t = 0; t < TT; ++t) {
        const int p = t & 1;
        _Float16* i0r = in0 + p * 16 * S0;
        _Float16* i0w = in0 + (p ^ 1) * 16 * S0;
        _Float16* i1r = in1 + p * 16 * S1;
        _Float16* i1w = in1 + (p ^ 1) * 16 * S1;
        _Float16* i2r = in2 + p * 16 * S1;
        _Float16* i2w = in2 + (p ^ 1) * 16 * S1;

        // prefetch x_{t+1}
        const bool hasNext = (t + 1 < TT);
        float xr = 0.f;
        if (xok && hasNext) xr = xp[t + 1];

        // ================= layer 0 =================
        {
            float4v acc[4] = {float4v{0,0,0,0}, float4v{0,0,0,0}, float4v{0,0,0,0}, float4v{0,0,0,0}};
#pragma unroll
            for (int kt = 0; kt < 3; ++kt) {
                half8 a = *(const half8*)(i0r + arow0 + 32 * kt);
#pragma unroll
                for (int g = 0; g < 4; ++g)
                    acc[g] = __builtin_amdgcn_mfma_f32_16x16x32_f16(a, wf0[g][kt], acc[g], 0, 0, 0);
            }
            // redistribute: z[g][b=q][u] <- quad-0 lane l15, reg q
            float z[4];
#pragma unroll
            for (int g = 0; g < 4; ++g) {
                float t0 = __shfl(acc[g][0], l15);
                float t1 = __shfl(acc[g][1], l15);
                float t2 = __shfl(acc[g][2], l15);
                float t3 = __shfl(acc[g][3], l15);
                float lo = (q & 2) ? t2 : t0;
                float hi = (q & 2) ? t3 : t1;
                z[g] = (q & 1) ? hi : lo;
            }
            float zi = z[0] + biasv[0][0], zf = z[1] + biasv[0][1];
            float zg = z[2] + biasv[0][2], zo = z[3] + biasv[0][3];
            float cc = sigm(zf) * c0 + sigm(zi) * tanh_(zg);
            c0 = cc;
            float hh = sigm(zo) * tanh_(cc);
            _Float16 hf = (_Float16)hh;
            i0w[b * S0 + 32 + u] = hf; // own recurrence, next tick
            i1r[b * S1 + u]      = hf; // layer1 input, this tick
        }
        __syncthreads();

        // ================= layer 1 =================
        {
            float4v acc[4] = {float4v{0,0,0,0}, float4v{0,0,0,0}, float4v{0,0,0,0}, float4v{0,0,0,0}};
#pragma unroll
            for (int kt = 0; kt < 4; ++kt) {
                half8 a = *(const half8*)(i1r + arow1 + 32 * kt);
#pragma unroll
                for (int g = 0; g < 4; ++g)
                    acc[g] = __builtin_amdgcn_mfma_f32_16x16x32_f16(a, wf1[g][kt], acc[g], 0, 0, 0);
            }
            float z[4];
#pragma unroll
            for (int g = 0; g < 4; ++g) {
                float t0 = __shfl(acc[g][0], l15);
                float t1 = __shfl(acc[g][1], l15);
                float t2 = __shfl(acc[g][2], l15);
                float t3 = __shfl(acc[g][3], l15);
                float lo = (q & 2) ? t2 : t0;
                float hi = (q & 2) ? t3 : t1;
                z[g] = (q & 1) ? hi : lo;
            }
            float zi = z[0] + biasv[1][0], zf = z[1] + biasv[1][1];
            float zg = z[2] + biasv[1][2], zo = z[3] + biasv[1][3];
            float cc = sigm(zf) * c1 + sigm(zi) * tanh_(zg);
            c1 = cc;
            float hh = sigm(zo) * tanh_(cc);
            _Float16 hf = (_Float16)hh;
            i1w[b * S1 + 64 + u] = hf; // own recurrence
            i2r[b * S1 + u]      = hf; // layer2 input, this tick
        }
        __syncthreads();

        // ================= layer 2 =================
        {
            float4v acc[4] = {float4v{0,0,0,0}, float4v{0,0,0,0}, float4v{0,0,0,0}, float4v{0,0,0,0}};
#pragma unroll
            for (int kt = 0; kt < 4; ++kt) {
                half8 a = *(const half8*)(i2r + arow1 + 32 * kt);
#pragma unroll
                for (int g = 0; g < 4; ++g)
                    acc[g] = __builtin_amdgcn_mfma_f32_16x16x32_f16(a, wf2[g][kt], acc[g], 0, 0, 0);
            }
            float z[4];
#pragma unroll
            for (int g = 0; g < 4; ++g) {
                float t0 = __shfl(acc[g][0], l15);
                float t1 = __shfl(acc[g][1], l15);
                float t2 = __shfl(acc[g][2], l15);
                float t3 = __shfl(acc[g][3], l15);
                float lo = (q & 2) ? t2 : t0;
                float hi = (q & 2) ? t3 : t1;
                z[g] = (q & 1) ? hi : lo;
            }
            float zi = z[0] + biasv[2][0], zf = z[1] + biasv[2][1];
            float zg = z[2] + biasv[2][2], zo = z[3] + biasv[2][3];
            float cc = sigm(zf) * c2 + sigm(zi) * tanh_(zg);
            c2 = cc;
            float hh = sigm(zo) * tanh_(cc);
            i2w[b * S1 + 64 + u] = (_Float16)hh;
            if (t == TT - 1) fcA[b * 64 + u] = hh; // final h2 in fp32
        }

        // stage x_{t+1}
        if (xok && hasNext) i0w[xb * S0 + xf] = (_Float16)xr;
        __syncthreads();
    }

    // ================= FC head (fp32) =================
    // FC0: 64 -> 54, BN, ReLU   (fcA -> fcB)
    for (int i = tid; i < 54 * 64; i += 256) fcW[(i >> 6) * 65 + (i & 63)] = w0[i];
    for (int i = tid; i < 54; i += 256) {
        fcP[i] = b0[i]; fcP[64 + i] = g0[i]; fcP[128 + i] = be0[i];
        fcP[192 + i] = m0[i]; fcP[256 + i] = v0[i];
    }
    __syncthreads();
    for (int idx = tid; idx < BB * 54; idx += 256) {
        const int bb = idx / 54, j = idx - bb * 54;
        float s = fcP[j];
        for (int k = 0; k < 64; ++k) s += fcW[j * 65 + k] * fcA[bb * 64 + k];
        s = (s - fcP[192 + j]) * rsqrtf(fcP[256 + j] + 1e-5f) * fcP[64 + j] + fcP[128 + j];
        fcB[bb * 64 + j] = fmaxf(s, 0.0f);
    }
    __syncthreads();

    // FC1: 54 -> 44, BN, ReLU   (fcB -> fcA)
    for (int i = tid; i < 44 * 54; i += 256) fcW[(i / 54) * 55 + (i % 54)] = w1[i];
    for (int i = tid; i < 44; i += 256) {
        fcP[i] = b1[i]; fcP[64 + i] = g1[i]; fcP[128 + i] = be1[i];
        fcP[192 + i] = m1[i]; fcP[256 + i] = v1[i];
    }
    __syncthreads();
    for (int idx = tid; idx < BB * 44; idx += 256) {
        const int bb = idx / 44, j = idx - bb * 44;
        float s = fcP[j];
        for (int k = 0; k < 54; ++k) s += fcW[j * 55 + k] * fcB[bb * 64 + k];
        s = (s - fcP[192 + j]) * rsqrtf(fcP[256 + j] + 1e-5f) * fcP[64 + j] + fcP[128 + j];
        fcA[bb * 64 + j] = fmaxf(s, 0.0f);
    }
    __syncthreads();

    // FC2: 44 -> 24, BN, ReLU   (fcA -> fcB)
    for (int i = tid; i < 24 * 44; i += 256) fcW[(i / 44) * 45 + (i % 44)] = w2[i];
    for (int i = tid; i < 24; i += 256) {
        fcP[i] = b2[i]; fcP[64 + i] = g2[i]; fcP[128 + i] = be2[i];
        fcP[192 + i] = m2[i]; fcP[256 + i] = v2[i];
    }
    __syncthreads();
    for (int idx = tid; idx < BB * 24; idx += 256) {
        const int bb = idx / 24, j = idx - bb * 24;
        float s = fcP[j];
        for (int k = 0; k < 44; ++k) s += fcW[j * 45 + k] * fcA[bb * 64 + k];
        s = (s - fcP[192 + j]) * rsqrtf(fcP[256 + j] + 1e-5f) * fcP[64 + j] + fcP[128 + j];
        fcB[bb * 64 + j] = fmaxf(s, 0.0f);
    }
    __syncthreads();

    // FC3: 24 -> 4 -> global out
    for (int i = tid; i < 4 * 24; i += 256) fcW[(i / 24) * 25 + (i % 24)] = w3[i];
    for (int i = tid; i < 4; i += 256) fcP[i] = b3[i];
    __syncthreads();
    for (int idx = tid; idx < BB * 4; idx += 256) {
        const int bb = idx / 4, j = idx - bb * 4;
        float s = fcP[j];
        for (int k = 0; k < 24; ++k) s += fcW[j * 25 + k] * fcB[bb * 64 + k];
        out[(size_t)(n0 + bb) * 4 + j] = s;
    }
}

extern "C" void kernel_launch(void* const* d_in, const int* in_sizes, int n_in,
                              void* d_out, int out_size, void* d_ws, size_t ws_size,
                              hipStream_t stream) {
    const float* p[33];
    for (int i = 0; i < 33; ++i) p[i] = (const float*)d_in[i];
    lstm_fused<<<NBLK, 256, 0, stream>>>(
        p[0],
        p[1], p[2], p[3], p[4],
        p[5], p[6], p[7], p[8],
        p[9], p[10], p[11], p[12],
        p[13], p[14], p[15], p[16], p[17], p[18], p[19], p[20],
        p[21], p[22], p[23], p[24],
        p[25], p[26], p[27], p[28],
        p[29], p[30], p[31], p[32],
        (float*)d_out);
}

// Round 3
// 1723.037 us; speedup vs baseline: 1.8034x; 1.1532x over previous
//
#include <hip/hip_runtime.h>
#include <hip/hip_fp16.h>

// N=1024, F=22, T=1000, H=64, gates 4H=256
// Diagonal pipeline: iteration i computes L0(t=i), L1(t=i-1), L2(t=i-2);
// all three only read iteration i-1 outputs -> ONE barrier per iteration.
#define TT 1000
#define FF 22
#define HH 64
#define BB 4       // batch per block (M-tile padded to 16; valid C rows in quad 0)
#define NBLK 256   // 1024/4 -> one block per CU
#define S0 112     // LDS row stride (f16) layer0 [x(0:22)|pad|h0(32:96)|pad], 3 K-tiles
#define S1 144     // LDS row stride (f16) layers1/2 [h_in(0:64)|h_rec(64:128)|pad], 4 K-tiles

typedef _Float16 half8 __attribute__((ext_vector_type(8)));
typedef float float4v __attribute__((ext_vector_type(4)));

__device__ __forceinline__ float sigm(float v) { return 1.0f / (1.0f + __expf(-v)); }
__device__ __forceinline__ float tanh_(float v) { return 1.0f - 2.0f / (__expf(2.0f * v) + 1.0f); }

template<int KT>
__device__ __forceinline__ void gemm_tile(const _Float16* __restrict__ rd, int arow,
                                          const half8 wf[][KT], float4v acc[4]) {
#pragma unroll
    for (int kt = 0; kt < KT; ++kt) {
        half8 a = *(const half8*)(rd + arow + 32 * kt);
#pragma unroll
        for (int g = 0; g < 4; ++g)
            acc[g] = __builtin_amdgcn_mfma_f32_16x16x32_f16(a, wf[g][kt], acc[g], 0, 0, 0);
    }
}

__device__ __forceinline__ void exchange(const float4v acc[4], int q, int l15, float z[4]) {
#pragma unroll
    for (int g = 0; g < 4; ++g) {
        float t0 = __shfl(acc[g][0], l15);
        float t1 = __shfl(acc[g][1], l15);
        float t2 = __shfl(acc[g][2], l15);
        float t3 = __shfl(acc[g][3], l15);
        float lo = (q & 2) ? t2 : t0;
        float hi = (q & 2) ? t3 : t1;
        z[g] = (q & 1) ? hi : lo;
    }
}

__device__ __forceinline__ float gate_update(const float z[4], const float bias[4], float& c) {
    float zi = z[0] + bias[0], zf = z[1] + bias[1];
    float zg = z[2] + bias[2], zo = z[3] + bias[3];
    float cc = sigm(zf) * c + sigm(zi) * tanh_(zg);
    c = cc;
    return sigm(zo) * tanh_(cc);
}

extern "C" __global__ void __launch_bounds__(256, 1)
lstm_fused(const float* __restrict__ x,
           const float* __restrict__ Wih0, const float* __restrict__ Whh0,
           const float* __restrict__ bih0, const float* __restrict__ bhh0,
           const float* __restrict__ Wih1, const float* __restrict__ Whh1,
           const float* __restrict__ bih1, const float* __restrict__ bhh1,
           const float* __restrict__ Wih2, const float* __restrict__ Whh2,
           const float* __restrict__ bih2, const float* __restrict__ bhh2,
           const float* __restrict__ w0, const float* __restrict__ b0,
           const float* __restrict__ w1, const float* __restrict__ b1,
           const float* __restrict__ w2, const float* __restrict__ b2,
           const float* __restrict__ w3, const float* __restrict__ b3,
           const float* __restrict__ g0, const float* __restrict__ be0,
           const float* __restrict__ m0, const float* __restrict__ v0,
           const float* __restrict__ g1, const float* __restrict__ be1,
           const float* __restrict__ m1, const float* __restrict__ v1,
           const float* __restrict__ g2, const float* __restrict__ be2,
           const float* __restrict__ m2, const float* __restrict__ v2,
           float* __restrict__ out)
{
    __shared__ __align__(16) _Float16 in0[2 * 16 * S0];
    __shared__ __align__(16) _Float16 in1[2 * 16 * S1];
    __shared__ __align__(16) _Float16 in2[2 * 16 * S1];
    __shared__ float fcA[BB * 64];
    __shared__ float fcB[BB * 64];
    __shared__ float fcW[54 * 65];
    __shared__ float fcP[5 * 64];

    const int tid = threadIdx.x;
    const int w   = tid >> 6;
    const int l   = tid & 63;
    const int q   = l >> 4;
    const int l15 = l & 15;
    const int u   = 16 * w + l15; // gate-update role: hidden unit
    const int b   = q;            // gate-update role: batch row
    const int n0  = blockIdx.x * BB;

    for (int i = tid; i < 2 * 16 * S0; i += 256) in0[i] = (_Float16)0.0f;
    for (int i = tid; i < 2 * 16 * S1; i += 256) in1[i] = (_Float16)0.0f;
    for (int i = tid; i < 2 * 16 * S1; i += 256) in2[i] = (_Float16)0.0f;

    // ---- weight B-fragments in registers ----
    half8 wf0[4][3], wf1[4][4], wf2[4][4];
    float bias0[4], bias1[4], bias2[4];
#pragma unroll
    for (int g = 0; g < 4; ++g) {
        const int row = 64 * g + u;
#pragma unroll
        for (int kt = 0; kt < 3; ++kt) {
            half8 h{};
#pragma unroll
            for (int j = 0; j < 8; ++j) {
                const int k = 32 * kt + 8 * q + j;
                float val = 0.0f;
                if (k < 32) { if (k < FF) val = Wih0[row * FF + k]; }
                else        { val = Whh0[row * HH + (k - 32)]; }
                h[j] = (_Float16)val;
            }
            wf0[g][kt] = h;
        }
        bias0[g] = bih0[row] + bhh0[row];
#pragma unroll
        for (int kt = 0; kt < 4; ++kt) {
            half8 ha{}, hb{};
#pragma unroll
            for (int j = 0; j < 8; ++j) {
                const int k = 32 * kt + 8 * q + j;
                ha[j] = (_Float16)((k < 64) ? Wih1[row * HH + k] : Whh1[row * HH + (k - 64)]);
                hb[j] = (_Float16)((k < 64) ? Wih2[row * HH + k] : Whh2[row * HH + (k - 64)]);
            }
            wf1[g][kt] = ha;
            wf2[g][kt] = hb;
        }
        bias1[g] = bih1[row] + bhh1[row];
        bias2[g] = bih2[row] + bhh2[row];
    }

    // ---- x staging: BB*FF = 88 items, one thread each ----
    const bool xok = (tid < BB * FF);
    const int  xb  = xok ? (tid / FF) : 0;
    const int  xf  = xok ? (tid - xb * FF) : 0;
    const float* xp = x + ((size_t)(n0 + xb) * FF + xf) * TT;

    __syncthreads();
    if (xok) in0[xb * S0 + xf] = (_Float16)xp[0]; // x_0 -> parity 0
    __syncthreads();

    const int arow0 = l15 * S0 + q * 8;
    const int arow1 = l15 * S1 + q * 8;
    const int wr0   = b * S0 + 32 + u;  // h0 recurrence slot
    const int wi1   = b * S1 + u;       // layer1 input slot
    const int wr1   = b * S1 + 64 + u;  // h1 recurrence slot
    const int wi2   = b * S1 + u;       // layer2 input slot
    const int wr2   = b * S1 + 64 + u;  // h2 recurrence slot

    float c0 = 0.f, c1 = 0.f, c2 = 0.f;

    // ================= prologue: i = 0 (L0 only) =================
    {
        _Float16* i0r = in0;                _Float16* i0w = in0 + 16 * S0;
        _Float16* i1w = in1 + 16 * S1;
        float xr = 0.f; if (xok) xr = xp[1];
        float4v acc[4] = {float4v{0,0,0,0}, float4v{0,0,0,0}, float4v{0,0,0,0}, float4v{0,0,0,0}};
        gemm_tile<3>(i0r, arow0, wf0, acc);
        float z[4]; exchange(acc, q, l15, z);
        float h0 = gate_update(z, bias0, c0);
        _Float16 hf = (_Float16)h0;
        i0w[wr0] = hf; i1w[wi1] = hf;
        if (xok) i0w[xb * S0 + xf] = (_Float16)xr;
        __syncthreads();
    }
    // ================= prologue: i = 1 (L0, L1) =================
    {
        _Float16* i0r = in0 + 16 * S0;      _Float16* i0w = in0;
        _Float16* i1r = in1 + 16 * S1;      _Float16* i1w = in1;
        _Float16* i2w = in2;
        float xr = 0.f; if (xok) xr = xp[2];
        float4v a0[4] = {float4v{0,0,0,0}, float4v{0,0,0,0}, float4v{0,0,0,0}, float4v{0,0,0,0}};
        float4v a1[4] = {float4v{0,0,0,0}, float4v{0,0,0,0}, float4v{0,0,0,0}, float4v{0,0,0,0}};
        gemm_tile<3>(i0r, arow0, wf0, a0);
        gemm_tile<4>(i1r, arow1, wf1, a1);
        float z0[4], z1[4];
        exchange(a0, q, l15, z0);
        exchange(a1, q, l15, z1);
        float h0 = gate_update(z0, bias0, c0);
        float h1 = gate_update(z1, bias1, c1);
        _Float16 hf0 = (_Float16)h0, hf1 = (_Float16)h1;
        i0w[wr0] = hf0; i1w[wi1] = hf0;
        i1w[wr1] = hf1; i2w[wi2] = hf1;
        if (xok) i0w[xb * S0 + xf] = (_Float16)xr;
        __syncthreads();
    }

    // ================= steady state: i = 2 .. TT-1 (branch-free) =================
    for (int i = 2; i < TT; ++i) {
        const int p = i & 1;
        _Float16* i0r = in0 + p * 16 * S0;  _Float16* i0w = in0 + (p ^ 1) * 16 * S0;
        _Float16* i1r = in1 + p * 16 * S1;  _Float16* i1w = in1 + (p ^ 1) * 16 * S1;
        _Float16* i2r = in2 + p * 16 * S1;  _Float16* i2w = in2 + (p ^ 1) * 16 * S1;

        const int tn = (i + 1 < TT) ? (i + 1) : (TT - 1); // clamped; clamp case never read
        float xr = 0.f; if (xok) xr = xp[tn];

        float4v a0[4] = {float4v{0,0,0,0}, float4v{0,0,0,0}, float4v{0,0,0,0}, float4v{0,0,0,0}};
        float4v a1[4] = {float4v{0,0,0,0}, float4v{0,0,0,0}, float4v{0,0,0,0}, float4v{0,0,0,0}};
        float4v a2[4] = {float4v{0,0,0,0}, float4v{0,0,0,0}, float4v{0,0,0,0}, float4v{0,0,0,0}};
        gemm_tile<3>(i0r, arow0, wf0, a0);   // L0 t=i
        gemm_tile<4>(i1r, arow1, wf1, a1);   // L1 t=i-1
        gemm_tile<4>(i2r, arow1, wf2, a2);   // L2 t=i-2

        float z0[4], z1[4], z2[4];
        exchange(a0, q, l15, z0);
        exchange(a1, q, l15, z1);
        exchange(a2, q, l15, z2);

        float h0 = gate_update(z0, bias0, c0);
        float h1 = gate_update(z1, bias1, c1);
        float h2 = gate_update(z2, bias2, c2);

        _Float16 hf0 = (_Float16)h0, hf1 = (_Float16)h1;
        i0w[wr0] = hf0; i1w[wi1] = hf0;
        i1w[wr1] = hf1; i2w[wi2] = hf1;
        i2w[wr2] = (_Float16)h2;
        if (xok) i0w[xb * S0 + xf] = (_Float16)xr;
        __syncthreads();
    }

    // ================= epilogue: i = TT (L1 t=TT-1, L2 t=TT-2); TT even -> p=0 =================
    {
        _Float16* i1r = in1;                _Float16* i1w = in1 + 16 * S1;
        _Float16* i2r = in2;                _Float16* i2w = in2 + 16 * S1;
        float4v a1[4] = {float4v{0,0,0,0}, float4v{0,0,0,0}, float4v{0,0,0,0}, float4v{0,0,0,0}};
        float4v a2[4] = {float4v{0,0,0,0}, float4v{0,0,0,0}, float4v{0,0,0,0}, float4v{0,0,0,0}};
        gemm_tile<4>(i1r, arow1, wf1, a1);
        gemm_tile<4>(i2r, arow1, wf2, a2);
        float z1[4], z2[4];
        exchange(a1, q, l15, z1);
        exchange(a2, q, l15, z2);
        float h1 = gate_update(z1, bias1, c1);
        float h2 = gate_update(z2, bias2, c2);
        i1w[wr1] = (_Float16)h1; i2w[wi2] = (_Float16)h1;
        i2w[wr2] = (_Float16)h2;
        __syncthreads();
    }
    // ================= epilogue: i = TT+1 (L2 t=TT-1) =================
    {
        _Float16* i2r = in2 + 16 * S1;
        float4v a2[4] = {float4v{0,0,0,0}, float4v{0,0,0,0}, float4v{0,0,0,0}, float4v{0,0,0,0}};
        gemm_tile<4>(i2r, arow1, wf2, a2);
        float z2[4];
        exchange(a2, q, l15, z2);
        float h2 = gate_update(z2, bias2, c2);
        fcA[b * 64 + u] = h2; // final h2, fp32
        __syncthreads();
    }

    // ================= FC head (fp32) =================
    for (int i = tid; i < 54 * 64; i += 256) fcW[(i >> 6) * 65 + (i & 63)] = w0[i];
    for (int i = tid; i < 54; i += 256) {
        fcP[i] = b0[i]; fcP[64 + i] = g0[i]; fcP[128 + i] = be0[i];
        fcP[192 + i] = m0[i]; fcP[256 + i] = v0[i];
    }
    __syncthreads();
    for (int idx = tid; idx < BB * 54; idx += 256) {
        const int bb = idx / 54, j = idx - bb * 54;
        float s = fcP[j];
        for (int k = 0; k < 64; ++k) s += fcW[j * 65 + k] * fcA[bb * 64 + k];
        s = (s - fcP[192 + j]) * rsqrtf(fcP[256 + j] + 1e-5f) * fcP[64 + j] + fcP[128 + j];
        fcB[bb * 64 + j] = fmaxf(s, 0.0f);
    }
    __syncthreads();

    for (int i = tid; i < 44 * 54; i += 256) fcW[(i / 54) * 55 + (i % 54)] = w1[i];
    for (int i = tid; i < 44; i += 256) {
        fcP[i] = b1[i]; fcP[64 + i] = g1[i]; fcP[128 + i] = be1[i];
        fcP[192 + i] = m1[i]; fcP[256 + i] = v1[i];
    }
    __syncthreads();
    for (int idx = tid; idx < BB * 44; idx += 256) {
        const int bb = idx / 44, j = idx - bb * 44;
        float s = fcP[j];
        for (int k = 0; k < 54; ++k) s += fcW[j * 55 + k] * fcB[bb * 64 + k];
        s = (s - fcP[192 + j]) * rsqrtf(fcP[256 + j] + 1e-5f) * fcP[64 + j] + fcP[128 + j];
        fcA[bb * 64 + j] = fmaxf(s, 0.0f);
    }
    __syncthreads();

    for (int i = tid; i < 24 * 44; i += 256) fcW[(i / 44) * 45 + (i % 44)] = w2[i];
    for (int i = tid; i < 24; i += 256) {
        fcP[i] = b2[i]; fcP[64 + i] = g2[i]; fcP[128 + i] = be2[i];
        fcP[192 + i] = m2[i]; fcP[256 + i] = v2[i];
    }
    __syncthreads();
    for (int idx = tid; idx < BB * 24; idx += 256) {
        const int bb = idx / 24, j = idx - bb * 24;
        float s = fcP[j];
        for (int k = 0; k < 44; ++k) s += fcW[j * 45 + k] * fcA[bb * 64 + k];
        s = (s - fcP[192 + j]) * rsqrtf(fcP[256 + j] + 1e-5f) * fcP[64 + j] + fcP[128 + j];
        fcB[bb * 64 + j] = fmaxf(s, 0.0f);
    }
    __syncthreads();

    for (int i = tid; i < 4 * 24; i += 256) fcW[(i / 24) * 25 + (i % 24)] = w3[i];
    for (int i = tid; i < 4; i += 256) fcP[i] = b3[i];
    __syncthreads();
    for (int idx = tid; idx < BB * 4; idx += 256) {
        const int bb = idx / 4, j = idx - bb * 4;
        float s = fcP[j];
        for (int k = 0; k < 24; ++k) s += fcW[j * 25 + k] * fcB[bb * 64 + k];
        out[(size_t)(n0 + bb) * 4 + j] = s;
    }
}

extern "C" void kernel_launch(void* const* d_in, const int* in_sizes, int n_in,
                              void* d_out, int out_size, void* d_ws, size_t ws_size,
                              hipStream_t stream) {
    const float* p[33];
    for (int i = 0; i < 33; ++i) p[i] = (const float*)d_in[i];
    lstm_fused<<<NBLK, 256, 0, stream>>>(
        p[0],
        p[1], p[2], p[3], p[4],
        p[5], p[6], p[7], p[8],
        p[9], p[10], p[11], p[12],
        p[13], p[14], p[15], p[16], p[17], p[18], p[19], p[20],
        p[21], p[22], p[23], p[24],
        p[25], p[26], p[27], p[28],
        p[29], p[30], p[31], p[32],
        (float*)d_out);
}

// Round 4
// 1449.812 us; speedup vs baseline: 2.1433x; 1.1885x over previous
//
#include <hip/hip_runtime.h>
#include <hip/hip_fp16.h>

// N=1024, F=22, T=1000, H=64, gates 4H=256
// Diagonal pipeline (iter i: L0 t=i, L1 t=i-1, L2 t=i-2), ONE barrier/iter.
// 512 threads = 8 waves: waves 0-3 ("G2") own L2 unit for colgroup w;
// waves 4-7 ("G01") own L1+L0 units for colgroup w-4. 2 waves/SIMD hide latency.
#define TT 1000
#define FF 22
#define HH 64
#define BB 4       // batch per block (M-tile padded to 16; valid C rows in quad 0)
#define NBLK 256   // 1024/4 -> one block per CU
#define S0 112     // LDS row stride (f16) layer0 [x(0:22)|pad|h0(32:96)|pad], 3 K-tiles
#define S1 144     // LDS row stride (f16) layers1/2 [h_in(0:64)|h_rec(64:128)|pad], 4 K-tiles

typedef _Float16 half8 __attribute__((ext_vector_type(8)));
typedef float float4v __attribute__((ext_vector_type(4)));

__device__ __forceinline__ float sigm(float v) { return 1.0f / (1.0f + __expf(-v)); }
__device__ __forceinline__ float tanh_(float v) { return 1.0f - 2.0f / (__expf(2.0f * v) + 1.0f); }

__device__ __forceinline__ void exchange(const float4v acc[4], int q, int l15, float z[4]) {
#pragma unroll
    for (int g = 0; g < 4; ++g) {
        float t0 = __shfl(acc[g][0], l15);
        float t1 = __shfl(acc[g][1], l15);
        float t2 = __shfl(acc[g][2], l15);
        float t3 = __shfl(acc[g][3], l15);
        float lo = (q & 2) ? t2 : t0;
        float hi = (q & 2) ? t3 : t1;
        z[g] = (q & 1) ? hi : lo;
    }
}

__device__ __forceinline__ float gate_update(const float z[4], const float bias[4], float& c) {
    float zi = z[0] + bias[0], zf = z[1] + bias[1];
    float zg = z[2] + bias[2], zo = z[3] + bias[3];
    float cc = sigm(zf) * c + sigm(zi) * tanh_(zg);
    c = cc;
    return sigm(zo) * tanh_(cc);
}

extern "C" __global__ void __launch_bounds__(512, 1)
lstm_fused(const float* __restrict__ x,
           const float* __restrict__ Wih0, const float* __restrict__ Whh0,
           const float* __restrict__ bih0, const float* __restrict__ bhh0,
           const float* __restrict__ Wih1, const float* __restrict__ Whh1,
           const float* __restrict__ bih1, const float* __restrict__ bhh1,
           const float* __restrict__ Wih2, const float* __restrict__ Whh2,
           const float* __restrict__ bih2, const float* __restrict__ bhh2,
           const float* __restrict__ w0, const float* __restrict__ b0,
           const float* __restrict__ w1, const float* __restrict__ b1,
           const float* __restrict__ w2, const float* __restrict__ b2,
           const float* __restrict__ w3, const float* __restrict__ b3,
           const float* __restrict__ g0, const float* __restrict__ be0,
           const float* __restrict__ m0, const float* __restrict__ v0,
           const float* __restrict__ g1, const float* __restrict__ be1,
           const float* __restrict__ m1, const float* __restrict__ v1,
           const float* __restrict__ g2, const float* __restrict__ be2,
           const float* __restrict__ m2, const float* __restrict__ v2,
           float* __restrict__ out)
{
    __shared__ __align__(16) _Float16 in0[2 * 16 * S0];
    __shared__ __align__(16) _Float16 in1[2 * 16 * S1];
    __shared__ __align__(16) _Float16 in2[2 * 16 * S1];
    __shared__ float fcA[BB * 64];
    __shared__ float fcB[BB * 64];
    __shared__ float fcW[54 * 65];
    __shared__ float fcP[5 * 64];

    const int tid   = threadIdx.x;
    const bool isG01 = (tid >= 256);   // waves 4-7: L1 + L0 units
    const int w4    = (tid >> 6) & 3;  // colgroup within role
    const int l     = tid & 63;
    const int q     = l >> 4;
    const int l15   = l & 15;
    const int u     = 16 * w4 + l15;   // hidden unit for this lane's updates
    const int b     = q;               // batch row for this lane's updates
    const int n0    = blockIdx.x * BB;

    for (int i = tid; i < 2 * 16 * S0; i += 512) in0[i] = (_Float16)0.0f;
    for (int i = tid; i < 2 * 16 * S1; i += 512) in1[i] = (_Float16)0.0f;
    for (int i = tid; i < 2 * 16 * S1; i += 512) in2[i] = (_Float16)0.0f;

    // ---- weight B-fragments in registers ----
    // Unit A: G2 waves -> layer 2; G01 waves -> layer 1. Unit B: G01 only -> layer 0.
    const float* WihA = isG01 ? Wih1 : Wih2;
    const float* WhhA = isG01 ? Whh1 : Whh2;
    const float* bihA = isG01 ? bih1 : bih2;
    const float* bhhA = isG01 ? bhh1 : bhh2;

    half8 wfA[4][4], wfB[4][3];
    float biasA[4], biasB[4];
#pragma unroll
    for (int g = 0; g < 4; ++g) {
        const int row = 64 * g + u;
#pragma unroll
        for (int kt = 0; kt < 4; ++kt) {
            half8 h{};
#pragma unroll
            for (int j = 0; j < 8; ++j) {
                const int k = 32 * kt + 8 * q + j;
                h[j] = (_Float16)((k < 64) ? WihA[row * HH + k] : WhhA[row * HH + (k - 64)]);
            }
            wfA[g][kt] = h;
        }
        biasA[g] = bihA[row] + bhhA[row];
#pragma unroll
        for (int kt = 0; kt < 3; ++kt) {
            half8 h{};
#pragma unroll
            for (int j = 0; j < 8; ++j) {
                const int k = 32 * kt + 8 * q + j;
                float val = 0.0f;
                if (k < 32) { if (k < FF) val = Wih0[row * FF + k]; }
                else        { val = Whh0[row * HH + (k - 32)]; }
                h[j] = (_Float16)val;
            }
            wfB[g][kt] = h;
        }
        biasB[g] = bih0[row] + bhh0[row];
    }

    // ---- x staging: BB*FF = 88 items on tid<88 (waves 0-1, the light role) ----
    const bool xok = (tid < BB * FF);
    const int  xb  = xok ? (tid / FF) : 0;
    const int  xf  = xok ? (tid - xb * FF) : 0;
    const float* xp = x + ((size_t)(n0 + xb) * FF + xf) * TT;

    __syncthreads();
    if (xok) in0[xb * S0 + xf] = (_Float16)xp[0]; // x_0 -> parity 0
    __syncthreads();

    const int arow0 = l15 * S0 + q * 8;
    const int arow1 = l15 * S1 + q * 8;
    const int wrA   = b * S1 + 64 + u;  // h-rec slot (same formula for L1->in1, L2->in2)
    const int wiA   = b * S1 + u;       // input slot (L1's h -> in2; L0's h -> in1)
    const int wr0   = b * S0 + 32 + u;  // L0 h-rec slot in in0

    float cA = 0.f, cB = 0.f;  // G2: c2 ; G01: c1 and c0

    auto iter_body = [&](int i, bool d0, bool d1, bool d2, bool last) {
        const int p = i & 1;
        _Float16* i0r = in0 + p * 16 * S0;  _Float16* i0w = in0 + (p ^ 1) * 16 * S0;
        _Float16* i1r = in1 + p * 16 * S1;  _Float16* i1w = in1 + (p ^ 1) * 16 * S1;
        _Float16* i2r = in2 + p * 16 * S1;  _Float16* i2w = in2 + (p ^ 1) * 16 * S1;
        const _Float16* rdA = isG01 ? i1r : i2r;

        float xr = 0.f;
        if (d0 && xok) { const int tn = (i + 1 < TT) ? (i + 1) : (TT - 1); xr = xp[tn]; }

        const bool doA = isG01 ? d1 : d2;
        if (doA) {
            float4v acc[4] = {float4v{0,0,0,0}, float4v{0,0,0,0}, float4v{0,0,0,0}, float4v{0,0,0,0}};
#pragma unroll
            for (int kt = 0; kt < 4; ++kt) {
                half8 a = *(const half8*)(rdA + arow1 + 32 * kt);
#pragma unroll
                for (int g = 0; g < 4; ++g)
                    acc[g] = __builtin_amdgcn_mfma_f32_16x16x32_f16(a, wfA[g][kt], acc[g], 0, 0, 0);
            }
            float z[4]; exchange(acc, q, l15, z);
            float h = gate_update(z, biasA, cA);
            _Float16 hf = (_Float16)h;
            if (isG01) {            // h1: own recurrence + L2 input
                i1w[wrA] = hf; i2w[wiA] = hf;
            } else if (last) {      // final h2 -> FC input (fp32)
                fcA[b * 64 + u] = h;
            } else {                // h2: own recurrence
                i2w[wrA] = hf;
            }
        }
        if (isG01 && d0) {          // L0 unit
            float4v acc[4] = {float4v{0,0,0,0}, float4v{0,0,0,0}, float4v{0,0,0,0}, float4v{0,0,0,0}};
#pragma unroll
            for (int kt = 0; kt < 3; ++kt) {
                half8 a = *(const half8*)(i0r + arow0 + 32 * kt);
#pragma unroll
                for (int g = 0; g < 4; ++g)
                    acc[g] = __builtin_amdgcn_mfma_f32_16x16x32_f16(a, wfB[g][kt], acc[g], 0, 0, 0);
            }
            float z[4]; exchange(acc, q, l15, z);
            float h = gate_update(z, biasB, cB);
            _Float16 hf = (_Float16)h;
            i0w[wr0] = hf;          // h0: own recurrence
            i1w[wiA] = hf;          // L1 input
        }
        if (d0 && xok) i0w[xb * S0 + xf] = (_Float16)xr;
        __syncthreads();
    };

    iter_body(0, true, false, false, false);
    iter_body(1, true, true, false, false);
    for (int i = 2; i < TT; ++i)
        iter_body(i, true, true, true, false);
    iter_body(TT,     false, true,  true, false);
    iter_body(TT + 1, false, false, true, true);

    // ================= FC head (fp32) =================
    for (int i = tid; i < 54 * 64; i += 512) fcW[(i >> 6) * 65 + (i & 63)] = w0[i];
    for (int i = tid; i < 54; i += 512) {
        fcP[i] = b0[i]; fcP[64 + i] = g0[i]; fcP[128 + i] = be0[i];
        fcP[192 + i] = m0[i]; fcP[256 + i] = v0[i];
    }
    __syncthreads();
    for (int idx = tid; idx < BB * 54; idx += 512) {
        const int bb = idx / 54, j = idx - bb * 54;
        float s = fcP[j];
        for (int k = 0; k < 64; ++k) s += fcW[j * 65 + k] * fcA[bb * 64 + k];
        s = (s - fcP[192 + j]) * rsqrtf(fcP[256 + j] + 1e-5f) * fcP[64 + j] + fcP[128 + j];
        fcB[bb * 64 + j] = fmaxf(s, 0.0f);
    }
    __syncthreads();

    for (int i = tid; i < 44 * 54; i += 512) fcW[(i / 54) * 55 + (i % 54)] = w1[i];
    for (int i = tid; i < 44; i += 512) {
        fcP[i] = b1[i]; fcP[64 + i] = g1[i]; fcP[128 + i] = be1[i];
        fcP[192 + i] = m1[i]; fcP[256 + i] = v1[i];
    }
    __syncthreads();
    for (int idx = tid; idx < BB * 44; idx += 512) {
        const int bb = idx / 44, j = idx - bb * 44;
        float s = fcP[j];
        for (int k = 0; k < 54; ++k) s += fcW[j * 55 + k] * fcB[bb * 64 + k];
        s = (s - fcP[192 + j]) * rsqrtf(fcP[256 + j] + 1e-5f) * fcP[64 + j] + fcP[128 + j];
        fcA[bb * 64 + j] = fmaxf(s, 0.0f);
    }
    __syncthreads();

    for (int i = tid; i < 24 * 44; i += 512) fcW[(i / 44) * 45 + (i % 44)] = w2[i];
    for (int i = tid; i < 24; i += 512) {
        fcP[i] = b2[i]; fcP[64 + i] = g2[i]; fcP[128 + i] = be2[i];
        fcP[192 + i] = m2[i]; fcP[256 + i] = v2[i];
    }
    __syncthreads();
    for (int idx = tid; idx < BB * 24; idx += 512) {
        const int bb = idx / 24, j = idx - bb * 24;
        float s = fcP[j];
        for (int k = 0; k < 44; ++k) s += fcW[j * 45 + k] * fcA[bb * 64 + k];
        s = (s - fcP[192 + j]) * rsqrtf(fcP[256 + j] + 1e-5f) * fcP[64 + j] + fcP[128 + j];
        fcB[bb * 64 + j] = fmaxf(s, 0.0f);
    }
    __syncthreads();

    for (int i = tid; i < 4 * 24; i += 512) fcW[(i / 24) * 25 + (i % 24)] = w3[i];
    for (int i = tid; i < 4; i += 512) fcP[i] = b3[i];
    __syncthreads();
    for (int idx = tid; idx < BB * 4; idx += 512) {
        const int bb = idx / 4, j = idx - bb * 4;
        float s = fcP[j];
        for (int k = 0; k < 24; ++k) s += fcW[j * 25 + k] * fcB[bb * 64 + k];
        out[(size_t)(n0 + bb) * 4 + j] = s;
    }
}

extern "C" void kernel_launch(void* const* d_in, const int* in_sizes, int n_in,
                              void* d_out, int out_size, void* d_ws, size_t ws_size,
                              hipStream_t stream) {
    const float* p[33];
    for (int i = 0; i < 33; ++i) p[i] = (const float*)d_in[i];
    lstm_fused<<<NBLK, 512, 0, stream>>>(
        p[0],
        p[1], p[2], p[3], p[4],
        p[5], p[6], p[7], p[8],
        p[9], p[10], p[11], p[12],
        p[13], p[14], p[15], p[16], p[17], p[18], p[19], p[20],
        p[21], p[22], p[23], p[24],
        p[25], p[26], p[27], p[28],
        p[29], p[30], p[31], p[32],
        (float*)d_out);
}

// Round 5
// 1202.507 us; speedup vs baseline: 2.5841x; 1.2057x over previous
//
#include <hip/hip_runtime.h>
#include <hip/hip_fp16.h>

// N=1024, F=22, T=1000, H=64, gates 4H=256
// Diagonal pipeline (iter i: L0 t=i, L1 t=i-1, L2 t=i-2), ONE barrier/iter.
// 512 threads = 8 waves: waves 0-3 ("G2") own L2 unit for colgroup w;
// waves 4-7 ("G01") own L1+L0 units. 2 waves/SIMD hide latency.
// KEY (R5): A-rows replicated via addressing (row = l15&3) so C reg r = batch r
// for every lane -> gate z selected in-register (3 cndmask), NO cross-lane exchange.
#define TT 1000
#define FF 22
#define HH 64
#define BB 4       // batch per block
#define NBLK 256   // 1024/4 -> one block per CU
#define S0 112     // LDS row stride (f16) layer0 [x(0:22)|pad|h0(32:96)|pad], 3 K-tiles
#define S1 144     // LDS row stride (f16) layers1/2 [h_in(0:64)|h_rec(64:128)|pad], 4 K-tiles

typedef _Float16 half8 __attribute__((ext_vector_type(8)));
typedef float float4v __attribute__((ext_vector_type(4)));

__device__ __forceinline__ float sigm(float v) { return 1.0f / (1.0f + __expf(-v)); }
__device__ __forceinline__ float tanh_(float v) { return 1.0f - 2.0f / (__expf(2.0f * v) + 1.0f); }

// select reg q of a float4v acc (q in 0..3) with 3 cndmasks
__device__ __forceinline__ float sel4(const float4v a, int q) {
    float lo = (q & 2) ? a[2] : a[0];
    float hi = (q & 2) ? a[3] : a[1];
    return (q & 1) ? hi : lo;
}

__device__ __forceinline__ float gate_update(const float z[4], float& c) {
    float cc = sigm(z[1]) * c + sigm(z[0]) * tanh_(z[2]);
    c = cc;
    return sigm(z[3]) * tanh_(cc);
}

extern "C" __global__ void __launch_bounds__(512, 1)
lstm_fused(const float* __restrict__ x,
           const float* __restrict__ Wih0, const float* __restrict__ Whh0,
           const float* __restrict__ bih0, const float* __restrict__ bhh0,
           const float* __restrict__ Wih1, const float* __restrict__ Whh1,
           const float* __restrict__ bih1, const float* __restrict__ bhh1,
           const float* __restrict__ Wih2, const float* __restrict__ Whh2,
           const float* __restrict__ bih2, const float* __restrict__ bhh2,
           const float* __restrict__ w0, const float* __restrict__ b0,
           const float* __restrict__ w1, const float* __restrict__ b1,
           const float* __restrict__ w2, const float* __restrict__ b2,
           const float* __restrict__ w3, const float* __restrict__ b3,
           const float* __restrict__ g0, const float* __restrict__ be0,
           const float* __restrict__ m0, const float* __restrict__ v0,
           const float* __restrict__ g1, const float* __restrict__ be1,
           const float* __restrict__ m1, const float* __restrict__ v1,
           const float* __restrict__ g2, const float* __restrict__ be2,
           const float* __restrict__ m2, const float* __restrict__ v2,
           float* __restrict__ out)
{
    __shared__ __align__(16) _Float16 in0[2 * 4 * S0];
    __shared__ __align__(16) _Float16 in1[2 * 4 * S1];
    __shared__ __align__(16) _Float16 in2[2 * 4 * S1];
    __shared__ float fcA[BB * 64];
    __shared__ float fcB[BB * 64];
    __shared__ float fcW[54 * 65];
    __shared__ float fcP[5 * 64];

    const int tid   = threadIdx.x;
    const bool isG01 = (tid >= 256);   // waves 4-7: L1 + L0 units
    const int w4    = (tid >> 6) & 3;  // colgroup within role
    const int l     = tid & 63;
    const int q     = l >> 4;
    const int l15   = l & 15;
    const int u     = 16 * w4 + l15;   // hidden unit for this lane's update
    const int b     = q;               // batch row for this lane's update
    const int n0    = blockIdx.x * BB;

    for (int i = tid; i < 2 * 4 * S0; i += 512) in0[i] = (_Float16)0.0f;
    for (int i = tid; i < 2 * 4 * S1; i += 512) in1[i] = (_Float16)0.0f;
    for (int i = tid; i < 2 * 4 * S1; i += 512) in2[i] = (_Float16)0.0f;

    // ---- weight B-fragments in registers ----
    // Unit A: G2 waves -> layer 2; G01 waves -> layer 1. Unit B: G01 only -> layer 0.
    const float* WihA = isG01 ? Wih1 : Wih2;
    const float* WhhA = isG01 ? Whh1 : Whh2;
    const float* bihA = isG01 ? bih1 : bih2;
    const float* bhhA = isG01 ? bhh1 : bhh2;

    half8 wfA[4][4], wfB[4][3];
    float biasA[4], biasB[4];
#pragma unroll
    for (int g = 0; g < 4; ++g) {
        const int row = 64 * g + u;
#pragma unroll
        for (int kt = 0; kt < 4; ++kt) {
            half8 h{};
#pragma unroll
            for (int j = 0; j < 8; ++j) {
                const int k = 32 * kt + 8 * q + j;
                h[j] = (_Float16)((k < 64) ? WihA[row * HH + k] : WhhA[row * HH + (k - 64)]);
            }
            wfA[g][kt] = h;
        }
        biasA[g] = bihA[row] + bhhA[row];
#pragma unroll
        for (int kt = 0; kt < 3; ++kt) {
            half8 h{};
#pragma unroll
            for (int j = 0; j < 8; ++j) {
                const int k = 32 * kt + 8 * q + j;
                float val = 0.0f;
                if (k < 32) { if (k < FF) val = Wih0[row * FF + k]; }
                else        { val = Whh0[row * HH + (k - 32)]; }
                h[j] = (_Float16)val;
            }
            wfB[g][kt] = h;
        }
        biasB[g] = bih0[row] + bhh0[row];
    }

    // ---- x staging: BB*FF = 88 items on tid<88 ----
    const bool xok = (tid < BB * FF);
    const int  xb  = xok ? (tid / FF) : 0;
    const int  xf  = xok ? (tid - xb * FF) : 0;
    const float* xp = x + ((size_t)(n0 + xb) * FF + xf) * TT;

    __syncthreads();
    if (xok) in0[xb * S0 + xf] = (_Float16)xp[0]; // x_0 -> parity 0
    __syncthreads();

    // A-frag read: replicated rows via addressing (row = l15 & 3)
    const int arow0 = (l15 & 3) * S0 + q * 8;
    const int arow1 = (l15 & 3) * S1 + q * 8;
    const int wrA   = b * S1 + 64 + u;  // h-rec slot (L1->in1, L2->in2)
    const int wiA   = b * S1 + u;       // input slot (L1's h -> in2; L0's h -> in1)
    const int wr0   = b * S0 + 32 + u;  // L0 h-rec slot in in0

    float cA = 0.f, cB = 0.f;  // G2: c2 ; G01: c1 and c0

    auto iter_body = [&](int i, bool d0, bool d1, bool d2, bool last) {
        const int p = i & 1;
        _Float16* i0r = in0 + p * 4 * S0;  _Float16* i0w = in0 + (p ^ 1) * 4 * S0;
        _Float16* i1r = in1 + p * 4 * S1;  _Float16* i1w = in1 + (p ^ 1) * 4 * S1;
        _Float16* i2r = in2 + p * 4 * S1;  _Float16* i2w = in2 + (p ^ 1) * 4 * S1;
        const _Float16* rdA = isG01 ? i1r : i2r;

        float xr = 0.f;
        if (d0 && xok) { const int tn = (i + 1 < TT) ? (i + 1) : (TT - 1); xr = xp[tn]; }

        const bool doA = isG01 ? d1 : d2;
        if (doA) {
            float4v acc[4];
#pragma unroll
            for (int g = 0; g < 4; ++g)
                acc[g] = float4v{biasA[g], biasA[g], biasA[g], biasA[g]};
#pragma unroll
            for (int kt = 0; kt < 4; ++kt) {
                half8 a = *(const half8*)(rdA + arow1 + 32 * kt);
#pragma unroll
                for (int g = 0; g < 4; ++g)
                    acc[g] = __builtin_amdgcn_mfma_f32_16x16x32_f16(a, wfA[g][kt], acc[g], 0, 0, 0);
            }
            float z[4];
#pragma unroll
            for (int g = 0; g < 4; ++g) z[g] = sel4(acc[g], q);
            float h = gate_update(z, cA);
            _Float16 hf = (_Float16)h;
            if (isG01) {            // h1: own recurrence + L2 input
                i1w[wrA] = hf; i2w[wiA] = hf;
            } else if (last) {      // final h2 -> FC input (fp32)
                fcA[b * 64 + u] = h;
            } else {                // h2: own recurrence
                i2w[wrA] = hf;
            }
        }
        if (isG01 && d0) {          // L0 unit
            float4v acc[4];
#pragma unroll
            for (int g = 0; g < 4; ++g)
                acc[g] = float4v{biasB[g], biasB[g], biasB[g], biasB[g]};
#pragma unroll
            for (int kt = 0; kt < 3; ++kt) {
                half8 a = *(const half8*)(i0r + arow0 + 32 * kt);
#pragma unroll
                for (int g = 0; g < 4; ++g)
                    acc[g] = __builtin_amdgcn_mfma_f32_16x16x32_f16(a, wfB[g][kt], acc[g], 0, 0, 0);
            }
            float z[4];
#pragma unroll
            for (int g = 0; g < 4; ++g) z[g] = sel4(acc[g], q);
            float h = gate_update(z, cB);
            _Float16 hf = (_Float16)h;
            i0w[wr0] = hf;          // h0: own recurrence
            i1w[wiA] = hf;          // L1 input
        }
        if (d0 && xok) i0w[xb * S0 + xf] = (_Float16)xr;
        __syncthreads();
    };

    iter_body(0, true, false, false, false);
    iter_body(1, true, true, false, false);
    for (int i = 2; i < TT; ++i)
        iter_body(i, true, true, true, false);
    iter_body(TT,     false, true,  true, false);
    iter_body(TT + 1, false, false, true, true);

    // ================= FC head (fp32) =================
    for (int i = tid; i < 54 * 64; i += 512) fcW[(i >> 6) * 65 + (i & 63)] = w0[i];
    for (int i = tid; i < 54; i += 512) {
        fcP[i] = b0[i]; fcP[64 + i] = g0[i]; fcP[128 + i] = be0[i];
        fcP[192 + i] = m0[i]; fcP[256 + i] = v0[i];
    }
    __syncthreads();
    for (int idx = tid; idx < BB * 54; idx += 512) {
        const int bb = idx / 54, j = idx - bb * 54;
        float s = fcP[j];
        for (int k = 0; k < 64; ++k) s += fcW[j * 65 + k] * fcA[bb * 64 + k];
        s = (s - fcP[192 + j]) * rsqrtf(fcP[256 + j] + 1e-5f) * fcP[64 + j] + fcP[128 + j];
        fcB[bb * 64 + j] = fmaxf(s, 0.0f);
    }
    __syncthreads();

    for (int i = tid; i < 44 * 54; i += 512) fcW[(i / 54) * 55 + (i % 54)] = w1[i];
    for (int i = tid; i < 44; i += 512) {
        fcP[i] = b1[i]; fcP[64 + i] = g1[i]; fcP[128 + i] = be1[i];
        fcP[192 + i] = m1[i]; fcP[256 + i] = v1[i];
    }
    __syncthreads();
    for (int idx = tid; idx < BB * 44; idx += 512) {
        const int bb = idx / 44, j = idx - bb * 44;
        float s = fcP[j];
        for (int k = 0; k < 54; ++k) s += fcW[j * 55 + k] * fcB[bb * 64 + k];
        s = (s - fcP[192 + j]) * rsqrtf(fcP[256 + j] + 1e-5f) * fcP[64 + j] + fcP[128 + j];
        fcA[bb * 64 + j] = fmaxf(s, 0.0f);
    }
    __syncthreads();

    for (int i = tid; i < 24 * 44; i += 512) fcW[(i / 44) * 45 + (i % 44)] = w2[i];
    for (int i = tid; i < 24; i += 512) {
        fcP[i] = b2[i]; fcP[64 + i] = g2[i]; fcP[128 + i] = be2[i];
        fcP[192 + i] = m2[i]; fcP[256 + i] = v2[i];
    }
    __syncthreads();
    for (int idx = tid; idx < BB * 24; idx += 512) {
        const int bb = idx / 24, j = idx - bb * 24;
        float s = fcP[j];
        for (int k = 0; k < 44; ++k) s += fcW[j * 45 + k] * fcA[bb * 64 + k];
        s = (s - fcP[192 + j]) * rsqrtf(fcP[256 + j] + 1e-5f) * fcP[64 + j] + fcP[128 + j];
        fcB[bb * 64 + j] = fmaxf(s, 0.0f);
    }
    __syncthreads();

    for (int i = tid; i < 4 * 24; i += 512) fcW[(i / 24) * 25 + (i % 24)] = w3[i];
    for (int i = tid; i < 4; i += 512) fcP[i] = b3[i];
    __syncthreads();
    for (int idx = tid; idx < BB * 4; idx += 512) {
        const int bb = idx / 4, j = idx - bb * 4;
        float s = fcP[j];
        for (int k = 0; k < 24; ++k) s += fcW[j * 25 + k] * fcB[bb * 64 + k];
        out[(size_t)(n0 + bb) * 4 + j] = s;
    }
}

extern "C" void kernel_launch(void* const* d_in, const int* in_sizes, int n_in,
                              void* d_out, int out_size, void* d_ws, size_t ws_size,
                              hipStream_t stream) {
    const float* p[33];
    for (int i = 0; i < 33; ++i) p[i] = (const float*)d_in[i];
    lstm_fused<<<NBLK, 512, 0, stream>>>(
        p[0],
        p[1], p[2], p[3], p[4],
        p[5], p[6], p[7], p[8],
        p[9], p[10], p[11], p[12],
        p[13], p[14], p[15], p[16], p[17], p[18], p[19], p[20],
        p[21], p[22], p[23], p[24],
        p[25], p[26], p[27], p[28],
        p[29], p[30], p[31], p[32],
        (float*)d_out);
}

// Round 6
// 1149.056 us; speedup vs baseline: 2.7043x; 1.0465x over previous
//
#include <hip/hip_runtime.h>
#include <hip/hip_fp16.h>

// N=1024, F=22, T=1000, H=64, gates 4H=256
// Diagonal pipeline (iter i: L0 t=i, L1 t=i-1, L2 t=i-2), ONE barrier/iter.
// 1024 threads = 16 waves, ONE unit per wave:
//   waves 0-3: L2 colgroup w ; 4-7: L1 ; 8-11: L0 ; 12-15: x staging.
// SIMD s hosts {s, s+4, s+8, s+12}: 3 independent compute streams + stager
// cover each other's latencies. A-rows replicated via addressing (row=l15&3)
// so C reg r = batch r in every lane -> z selected with 3 cndmask, no exchange.
#define TT 1000
#define FF 22
#define HH 64
#define BB 4       // batch per block
#define NBLK 256   // 1024/4 -> one block per CU
#define S0 112     // LDS row stride (f16) layer0 [x(0:22)|pad|h0(32:96)|pad], 3 K-tiles
#define S1 144     // LDS row stride (f16) layers1/2 [h_in(0:64)|h_rec(64:128)|pad], 4 K-tiles

typedef _Float16 half8 __attribute__((ext_vector_type(8)));
typedef float float4v __attribute__((ext_vector_type(4)));

__device__ __forceinline__ float sigm(float v) { return 1.0f / (1.0f + __expf(-v)); }
__device__ __forceinline__ float tanh_(float v) { return 1.0f - 2.0f / (__expf(2.0f * v) + 1.0f); }

// select reg q of a float4v acc (q in 0..3) with 3 cndmasks
__device__ __forceinline__ float sel4(const float4v a, int q) {
    float lo = (q & 2) ? a[2] : a[0];
    float hi = (q & 2) ? a[3] : a[1];
    return (q & 1) ? hi : lo;
}

__device__ __forceinline__ float gate_update(const float z[4], float& c) {
    float cc = sigm(z[1]) * c + sigm(z[0]) * tanh_(z[2]);
    c = cc;
    return sigm(z[3]) * tanh_(cc);
}

extern "C" __global__ void __launch_bounds__(1024, 1)
lstm_fused(const float* __restrict__ x,
           const float* __restrict__ Wih0, const float* __restrict__ Whh0,
           const float* __restrict__ bih0, const float* __restrict__ bhh0,
           const float* __restrict__ Wih1, const float* __restrict__ Whh1,
           const float* __restrict__ bih1, const float* __restrict__ bhh1,
           const float* __restrict__ Wih2, const float* __restrict__ Whh2,
           const float* __restrict__ bih2, const float* __restrict__ bhh2,
           const float* __restrict__ w0, const float* __restrict__ b0,
           const float* __restrict__ w1, const float* __restrict__ b1,
           const float* __restrict__ w2, const float* __restrict__ b2,
           const float* __restrict__ w3, const float* __restrict__ b3,
           const float* __restrict__ g0, const float* __restrict__ be0,
           const float* __restrict__ m0, const float* __restrict__ v0,
           const float* __restrict__ g1, const float* __restrict__ be1,
           const float* __restrict__ m1, const float* __restrict__ v1,
           const float* __restrict__ g2, const float* __restrict__ be2,
           const float* __restrict__ m2, const float* __restrict__ v2,
           float* __restrict__ out)
{
    __shared__ __align__(16) _Float16 in0[2 * 4 * S0];
    __shared__ __align__(16) _Float16 in1[2 * 4 * S1];
    __shared__ __align__(16) _Float16 in2[2 * 4 * S1];
    __shared__ float fcA[BB * 64];
    __shared__ float fcB[BB * 64];
    __shared__ float fcW[54 * 65];
    __shared__ float fcP[5 * 64];

    const int tid  = threadIdx.x;
    const int wv   = tid >> 6;      // 0..15
    const int role = wv >> 2;       // 0=L2, 1=L1, 2=L0, 3=stage
    const int w4   = wv & 3;        // colgroup within role
    const int l    = tid & 63;
    const int q    = l >> 4;
    const int l15  = l & 15;
    const int u    = 16 * w4 + l15; // hidden unit for this lane's update
    const int b    = q;             // batch row for this lane's update
    const int n0   = blockIdx.x * BB;

    for (int i = tid; i < 2 * 4 * S0; i += 1024) in0[i] = (_Float16)0.0f;
    for (int i = tid; i < 2 * 4 * S1; i += 1024) in1[i] = (_Float16)0.0f;
    for (int i = tid; i < 2 * 4 * S1; i += 1024) in2[i] = (_Float16)0.0f;

    // ---- weight B-fragments: ONE unit per wave (shared reg array across roles) ----
    half8 wf[4][4];
    float bias[4];
    if (role == 2) {                 // layer 0: K=32(x,padded)+64(h) -> 3 K-tiles
#pragma unroll
        for (int g = 0; g < 4; ++g) {
            const int row = 64 * g + u;
#pragma unroll
            for (int kt = 0; kt < 3; ++kt) {
                half8 h{};
#pragma unroll
                for (int j = 0; j < 8; ++j) {
                    const int k = 32 * kt + 8 * q + j;
                    float val = 0.0f;
                    if (k < 32) { if (k < FF) val = Wih0[row * FF + k]; }
                    else        { val = Whh0[row * HH + (k - 32)]; }
                    h[j] = (_Float16)val;
                }
                wf[g][kt] = h;
            }
            bias[g] = bih0[row] + bhh0[row];
        }
    } else if (role < 2) {           // role 0 -> layer 2, role 1 -> layer 1 (K=128)
        const float* Wih = role ? Wih1 : Wih2;
        const float* Whh = role ? Whh1 : Whh2;
        const float* bih = role ? bih1 : bih2;
        const float* bhh = role ? bhh1 : bhh2;
#pragma unroll
        for (int g = 0; g < 4; ++g) {
            const int row = 64 * g + u;
#pragma unroll
            for (int kt = 0; kt < 4; ++kt) {
                half8 h{};
#pragma unroll
                for (int j = 0; j < 8; ++j) {
                    const int k = 32 * kt + 8 * q + j;
                    h[j] = (_Float16)((k < 64) ? Wih[row * HH + k] : Whh[row * HH + (k - 64)]);
                }
                wf[g][kt] = h;
            }
            bias[g] = bih[row] + bhh[row];
        }
    }

    // ---- x staging lanes: waves 12-15, first 88 threads of that group ----
    const int  st  = tid - 768;
    const bool xok = (role == 3) && (st < BB * FF);
    const int  xb  = xok ? (st / FF) : 0;
    const int  xf  = xok ? (st - xb * FF) : 0;
    const float* xp = x + ((size_t)(n0 + xb) * FF + xf) * TT;

    __syncthreads();
    if (xok) in0[xb * S0 + xf] = (_Float16)xp[0]; // x_0 -> parity 0
    __syncthreads();

    // A-frag read base: replicated rows via addressing (row = l15 & 3)
    const int arow = (role == 2) ? ((l15 & 3) * S0 + q * 8) : ((l15 & 3) * S1 + q * 8);

    float c = 0.f;  // this wave's cell state for its (layer, unit)

    auto iter_body = [&](int i, bool d0, bool d1, bool d2, bool last) {
        const int p = i & 1;
        _Float16* i0r = in0 + p * 4 * S0;  _Float16* i0w = in0 + (p ^ 1) * 4 * S0;
        _Float16* i1r = in1 + p * 4 * S1;  _Float16* i1w = in1 + (p ^ 1) * 4 * S1;
        _Float16* i2r = in2 + p * 4 * S1;  _Float16* i2w = in2 + (p ^ 1) * 4 * S1;

        if (role == 3) {
            if (d0 && xok) {
                const int tn = (i + 1 < TT) ? (i + 1) : (TT - 1); // clamp never read
                i0w[xb * S0 + xf] = (_Float16)xp[tn];
            }
        } else {
            const bool act = (role == 0) ? d2 : (role == 1) ? d1 : d0;
            if (act) {
                const _Float16* rd = (role == 0) ? i2r : (role == 1) ? i1r : i0r;
                float4v acc[4];
#pragma unroll
                for (int g = 0; g < 4; ++g)
                    acc[g] = float4v{bias[g], bias[g], bias[g], bias[g]};
                if (role == 2) {     // 3 K-tiles
                    half8 a0 = *(const half8*)(rd + arow);
                    half8 a1 = *(const half8*)(rd + arow + 32);
                    half8 a2 = *(const half8*)(rd + arow + 64);
#pragma unroll
                    for (int g = 0; g < 4; ++g)
                        acc[g] = __builtin_amdgcn_mfma_f32_16x16x32_f16(a0, wf[g][0], acc[g], 0, 0, 0);
#pragma unroll
                    for (int g = 0; g < 4; ++g)
                        acc[g] = __builtin_amdgcn_mfma_f32_16x16x32_f16(a1, wf[g][1], acc[g], 0, 0, 0);
#pragma unroll
                    for (int g = 0; g < 4; ++g)
                        acc[g] = __builtin_amdgcn_mfma_f32_16x16x32_f16(a2, wf[g][2], acc[g], 0, 0, 0);
                } else {             // 4 K-tiles
                    half8 a0 = *(const half8*)(rd + arow);
                    half8 a1 = *(const half8*)(rd + arow + 32);
                    half8 a2 = *(const half8*)(rd + arow + 64);
                    half8 a3 = *(const half8*)(rd + arow + 96);
#pragma unroll
                    for (int g = 0; g < 4; ++g)
                        acc[g] = __builtin_amdgcn_mfma_f32_16x16x32_f16(a0, wf[g][0], acc[g], 0, 0, 0);
#pragma unroll
                    for (int g = 0; g < 4; ++g)
                        acc[g] = __builtin_amdgcn_mfma_f32_16x16x32_f16(a1, wf[g][1], acc[g], 0, 0, 0);
#pragma unroll
                    for (int g = 0; g < 4; ++g)
                        acc[g] = __builtin_amdgcn_mfma_f32_16x16x32_f16(a2, wf[g][2], acc[g], 0, 0, 0);
#pragma unroll
                    for (int g = 0; g < 4; ++g)
                        acc[g] = __builtin_amdgcn_mfma_f32_16x16x32_f16(a3, wf[g][3], acc[g], 0, 0, 0);
                }
                float z[4];
#pragma unroll
                for (int g = 0; g < 4; ++g) z[g] = sel4(acc[g], q);
                float h = gate_update(z, c);
                _Float16 hf = (_Float16)h;
                if (role == 2) {        // h0: own recurrence + L1 input
                    i0w[b * S0 + 32 + u] = hf;
                    i1w[b * S1 + u]      = hf;
                } else if (role == 1) { // h1: own recurrence + L2 input
                    i1w[b * S1 + 64 + u] = hf;
                    i2w[b * S1 + u]      = hf;
                } else {                // L2
                    if (last) fcA[b * 64 + u] = h;     // final h2 -> FC (fp32)
                    else      i2w[b * S1 + 64 + u] = hf;
                }
            }
        }
        __syncthreads();
    };

    iter_body(0, true, false, false, false);
    iter_body(1, true, true, false, false);
    for (int i = 2; i < TT; ++i)
        iter_body(i, true, true, true, false);
    iter_body(TT,     false, true,  true, false);
    iter_body(TT + 1, false, false, true, true);

    // ================= FC head (fp32) =================
    for (int i = tid; i < 54 * 64; i += 1024) fcW[(i >> 6) * 65 + (i & 63)] = w0[i];
    for (int i = tid; i < 54; i += 1024) {
        fcP[i] = b0[i]; fcP[64 + i] = g0[i]; fcP[128 + i] = be0[i];
        fcP[192 + i] = m0[i]; fcP[256 + i] = v0[i];
    }
    __syncthreads();
    for (int idx = tid; idx < BB * 54; idx += 1024) {
        const int bb = idx / 54, j = idx - bb * 54;
        float s = fcP[j];
        for (int k = 0; k < 64; ++k) s += fcW[j * 65 + k] * fcA[bb * 64 + k];
        s = (s - fcP[192 + j]) * rsqrtf(fcP[256 + j] + 1e-5f) * fcP[64 + j] + fcP[128 + j];
        fcB[bb * 64 + j] = fmaxf(s, 0.0f);
    }
    __syncthreads();

    for (int i = tid; i < 44 * 54; i += 1024) fcW[(i / 54) * 55 + (i % 54)] = w1[i];
    for (int i = tid; i < 44; i += 1024) {
        fcP[i] = b1[i]; fcP[64 + i] = g1[i]; fcP[128 + i] = be1[i];
        fcP[192 + i] = m1[i]; fcP[256 + i] = v1[i];
    }
    __syncthreads();
    for (int idx = tid; idx < BB * 44; idx += 1024) {
        const int bb = idx / 44, j = idx - bb * 44;
        float s = fcP[j];
        for (int k = 0; k < 54; ++k) s += fcW[j * 55 + k] * fcB[bb * 64 + k];
        s = (s - fcP[192 + j]) * rsqrtf(fcP[256 + j] + 1e-5f) * fcP[64 + j] + fcP[128 + j];
        fcA[bb * 64 + j] = fmaxf(s, 0.0f);
    }
    __syncthreads();

    for (int i = tid; i < 24 * 44; i += 1024) fcW[(i / 44) * 45 + (i % 44)] = w2[i];
    for (int i = tid; i < 24; i += 1024) {
        fcP[i] = b2[i]; fcP[64 + i] = g2[i]; fcP[128 + i] = be2[i];
        fcP[192 + i] = m2[i]; fcP[256 + i] = v2[i];
    }
    __syncthreads();
    for (int idx = tid; idx < BB * 24; idx += 1024) {
        const int bb = idx / 24, j = idx - bb * 24;
        float s = fcP[j];
        for (int k = 0; k < 44; ++k) s += fcW[j * 45 + k] * fcA[bb * 64 + k];
        s = (s - fcP[192 + j]) * rsqrtf(fcP[256 + j] + 1e-5f) * fcP[64 + j] + fcP[128 + j];
        fcB[bb * 64 + j] = fmaxf(s, 0.0f);
    }
    __syncthreads();

    for (int i = tid; i < 4 * 24; i += 1024) fcW[(i / 24) * 25 + (i % 24)] = w3[i];
    for (int i = tid; i < 4; i += 1024) fcP[i] = b3[i];
    __syncthreads();
    for (int idx = tid; idx < BB * 4; idx += 1024) {
        const int bb = idx / 4, j = idx - bb * 4;
        float s = fcP[j];
        for (int k = 0; k < 24; ++k) s += fcW[j * 25 + k] * fcB[bb * 64 + k];
        out[(size_t)(n0 + bb) * 4 + j] = s;
    }
}

extern "C" void kernel_launch(void* const* d_in, const int* in_sizes, int n_in,
                              void* d_out, int out_size, void* d_ws, size_t ws_size,
                              hipStream_t stream) {
    const float* p[33];
    for (int i = 0; i < 33; ++i) p[i] = (const float*)d_in[i];
    lstm_fused<<<NBLK, 1024, 0, stream>>>(
        p[0],
        p[1], p[2], p[3], p[4],
        p[5], p[6], p[7], p[8],
        p[9], p[10], p[11], p[12],
        p[13], p[14], p[15], p[16], p[17], p[18], p[19], p[20],
        p[21], p[22], p[23], p[24],
        p[25], p[26], p[27], p[28],
        p[29], p[30], p[31], p[32],
        (float*)d_out);
}